// Round 12
// baseline (3015.226 us; speedup 1.0000x reference)
//
#include <hip/hip_runtime.h>
#include <math.h>

// Problem dims (fixed)
#define N_ 20000
#define E_ 100000
#define B_ 128
#define F_IN_ 14
#define DIM_ 64
#define E_FEAT_ 4
#define MLP_H_ 128
#define EWC_ 4096    // DIM*DIM
#define PC_ 8192     // MLP_H * DIM (P columns)

typedef __attribute__((ext_vector_type(4))) float f32x4;
typedef __attribute__((ext_vector_type(8))) _Float16 halfx8;
typedef __attribute__((ext_vector_type(2))) _Float16 half2v;

// ---------------------------------------------------------------------------
// lin0: out[n,d] = relu(x[n,:] @ lin0_w + b)
__global__ void lin0_kernel(const float* __restrict__ x, const float* __restrict__ w,
                            const float* __restrict__ b, float* __restrict__ out) {
    int idx = blockIdx.x * blockDim.x + threadIdx.x;
    if (idx >= N_ * DIM_) return;
    int n = idx >> 6, d = idx & 63;
    float acc = b[d];
#pragma unroll
    for (int f = 0; f < F_IN_; ++f) acc = fmaf(x[n * F_IN_ + f], w[f * DIM_ + d], acc);
    out[idx] = acc > 0.f ? acc : 0.f;
}

// edge MLP layer 1, ROW-major fp16: h1[e*128 + k] = relu(ea[e,:] @ w1 + b1)[k]
__global__ void mlp1_kernel(const float* __restrict__ ea, const float* __restrict__ w1,
                            const float* __restrict__ b1, _Float16* __restrict__ h1) {
    int idx = blockIdx.x * blockDim.x + threadIdx.x;
    if (idx >= E_ * MLP_H_) return;
    int e = idx >> 7, k = idx & 127;
    float acc = b1[k];
#pragma unroll
    for (int f = 0; f < E_FEAT_; ++f) acc = fmaf(ea[e * E_FEAT_ + f], w1[f * MLP_H_ + k], acc);
    h1[idx] = (_Float16)(acc > 0.f ? acc : 0.f);
}

// incoming-edge counts (float, for mean)
__global__ void cnt_kernel(const int* __restrict__ dst, float* __restrict__ cnt) {
    int e = blockIdx.x * blockDim.x + threadIdx.x;
    if (e >= E_) return;
    atomicAdd(&cnt[dst[e]], 1.0f);
}

// batch is SORTED: off_b[b] = lower_bound(batch, b).
__global__ void batch_off_kernel(const int* __restrict__ batch, int* __restrict__ off_b) {
    int b = threadIdx.x;
    if (b > B_) return;
    int lo = 0, hi = N_;
    while (lo < hi) {
        int mid = (lo + hi) >> 1;
        if (batch[mid] < b) lo = mid + 1; else hi = mid;
    }
    off_b[b] = lo;
}

// src histogram for counting sort
__global__ void hist_src(const int* __restrict__ src, int* __restrict__ cnt_src) {
    int e = blockIdx.x * blockDim.x + threadIdx.x;
    if (e >= E_) return;
    atomicAdd(&cnt_src[src[e]], 1);
}

// exclusive scan over N_ bins -> src_off[0..N_]
__global__ void scan_src(const int* __restrict__ cnt_src, int* __restrict__ src_off) {
    __shared__ int part[256];
    __shared__ int off[257];
    int t = threadIdx.x;
    const int per = (N_ + 255) / 256;
    int base = t * per;
    int s = 0;
    for (int i = 0; i < per; ++i) { int b = base + i; if (b < N_) s += cnt_src[b]; }
    part[t] = s;
    __syncthreads();
    if (t == 0) {
        int a = 0;
        for (int i = 0; i < 256; ++i) { off[i] = a; a += part[i]; }
        off[256] = a;
    }
    __syncthreads();
    int run = off[t];
    for (int i = 0; i < per; ++i) {
        int b = base + i;
        if (b < N_) { src_off[b] = run; run += cnt_src[b]; }
    }
    if (t == 0) src_off[N_] = off[256];
}

// scatter edges into src-sorted order
__global__ void scatter_src(const int* __restrict__ src, int* __restrict__ cur,
                            const int* __restrict__ src_off, int* __restrict__ eord) {
    int e = blockIdx.x * blockDim.x + threadIdx.x;
    if (e >= E_) return;
    int s = src[e];
    int p = src_off[s] + atomicAdd(&cur[s], 1);
    eord[p] = e;
}

// B prep (once), fp16, TRANSPOSED column order c = o*128 + k:
// Bf[c*64 + i] = (fp16) w2[k*4096 + i*64 + o]
__global__ void prep_b(const float* __restrict__ w2, _Float16* __restrict__ Bf) {
    int idx = blockIdx.x * blockDim.x + threadIdx.x;
    if (idx >= PC_ * 64) return;
    int c = idx >> 6, i = idx & 63;
    int o = c >> 7, k = c & 127;
    Bf[idx] = (_Float16)w2[(size_t)k * EWC_ + i * 64 + o];
}

// Q[n,o] = sum_i out[n,i] * b2[i*64+o] — wave/node, b2 staged in LDS
__global__ __launch_bounds__(256) void q_kernel(const float* __restrict__ out,
                                                const float* __restrict__ b2,
                                                float* __restrict__ Q) {
    __shared__ float b2s[64 * 64];
    int tid = threadIdx.x;
#pragma unroll
    for (int it = 0; it < 4; ++it) {
        int i = it * 1024 + tid * 4;
        *(float4*)&b2s[i] = *(const float4*)&b2[i];
    }
    __syncthreads();
    int wv = __builtin_amdgcn_readfirstlane(tid >> 6);
    int n = blockIdx.x * 4 + wv;
    if (n >= N_) return;
    int o = tid & 63;
    float ov = out[(size_t)n * 64 + o];
    float acc = 0.f;
#pragma unroll 8
    for (int i = 0; i < 64; ++i) acc = fmaf(__shfl(ov, i, 64), b2s[i * 64 + o], acc);
    Q[(size_t)n * 64 + o] = acc;
}

// ---------------------------------------------------------------------------
// Fused message kernel v4: P never materialized to global.
// Grid = (16 o-groups, 313 node-blocks). Block = 64 nodes x 512 cols
// (4 o-values x 128 k, transposed col order c = o*128+k).
// Phase A: P_tile = out[nb..nb+64, :] @ Bf[:, og*512..+512] via fp16 MFMA,
//          staged fp16 in LDS (pad 520 -> conflict-free). ONE barrier.
// Phase B: edges of the 64 nodes (src-sorted range, wave-strided): lanes =
//          (oi in [0,4)) x (kg in [0,16)); per edge 4x fdot2 over 8 k + 4-step
//          shfl_xor reduce; kg==0 lanes atomicAdd agg[dst*64 + og*4+oi].
#define NB_ 64
#define PSTR2_ 520   // fp16 row stride (1040 B -> quad rows land on distinct banks)
__global__ __launch_bounds__(256) void msg_fused(const float* __restrict__ out,
                                                 const _Float16* __restrict__ Bf,
                                                 const _Float16* __restrict__ h1,
                                                 const float* __restrict__ Q,
                                                 const int* __restrict__ eord,
                                                 const int* __restrict__ src,
                                                 const int* __restrict__ dst,
                                                 const int* __restrict__ src_off,
                                                 float* __restrict__ agg) {
    __shared__ _Float16 P_s[NB_ * PSTR2_];   // 66.6 KB
    int tid = threadIdx.x;
    int lane = tid & 63;
    int wv = tid >> 6;
    int lrow = lane & 15, quad = lane >> 4;
    int og = blockIdx.x;
    int nb = blockIdx.y * NB_;
    int cbase = og * 512 + wv * 128;         // wave's 128-col slice

    // ---- phase A ----
    halfx8 af[4][2];
#pragma unroll
    for (int mf = 0; mf < 4; ++mf) {
        int gm = nb + mf * 16 + lrow;
#pragma unroll
        for (int ks = 0; ks < 2; ++ks) {
            float v[8];
            if (gm < N_) {
                float4 v0 = *(const float4*)&out[(size_t)gm * 64 + ks * 32 + quad * 8];
                float4 v1 = *(const float4*)&out[(size_t)gm * 64 + ks * 32 + quad * 8 + 4];
                v[0] = v0.x; v[1] = v0.y; v[2] = v0.z; v[3] = v0.w;
                v[4] = v1.x; v[5] = v1.y; v[6] = v1.z; v[7] = v1.w;
            } else {
#pragma unroll
                for (int i = 0; i < 8; ++i) v[i] = 0.f;
            }
#pragma unroll
            for (int i = 0; i < 8; ++i) af[mf][ks][i] = (_Float16)v[i];
        }
    }
#pragma unroll
    for (int nf = 0; nf < 8; ++nf) {
        size_t c = (size_t)(cbase + nf * 16 + lrow);
        halfx8 b0 = *(const halfx8*)&Bf[c * 64 + quad * 8];
        halfx8 b1 = *(const halfx8*)&Bf[c * 64 + 32 + quad * 8];
#pragma unroll
        for (int mf = 0; mf < 4; ++mf) {
            f32x4 acc = (f32x4){0.f, 0.f, 0.f, 0.f};
            acc = __builtin_amdgcn_mfma_f32_16x16x32_f16(af[mf][0], b0, acc, 0, 0, 0);
            acc = __builtin_amdgcn_mfma_f32_16x16x32_f16(af[mf][1], b1, acc, 0, 0, 0);
            // C/D layout: col = lane&15 (c), row = quad*4+r (node) — m89-verified
#pragma unroll
            for (int r = 0; r < 4; ++r)
                P_s[(mf * 16 + quad * 4 + r) * PSTR2_ + wv * 128 + nf * 16 + lrow] =
                    (_Float16)acc[r];
        }
    }
    __syncthreads();

    // ---- phase B ----
    int nend = nb + NB_ < N_ ? nb + NB_ : N_;
    int beg = src_off[nb], end2 = src_off[nend];
    int oi = lane >> 4;           // [0,4)
    int kg = lane & 15;           // [0,16): k = kg*8 .. kg*8+7
    int obase = og * 4 + oi;
    for (int pos = beg + wv; pos < end2; pos += 4) {
        int ej = eord[pos];
        int s = src[ej];
        int d = dst[ej];
        halfx8 hv = *(const halfx8*)&h1[(size_t)ej * 128 + kg * 8];
        halfx8 pv = *(const halfx8*)&P_s[(s - nb) * PSTR2_ + oi * 128 + kg * 8];
        float p = 0.f;
#pragma unroll
        for (int i = 0; i < 4; ++i) {
            half2v ha = {hv[2 * i], hv[2 * i + 1]};
            half2v pa = {pv[2 * i], pv[2 * i + 1]};
            p = __builtin_amdgcn_fdot2(ha, pa, p, false);
        }
        p += __shfl_xor(p, 1, 64);
        p += __shfl_xor(p, 2, 64);
        p += __shfl_xor(p, 4, 64);
        p += __shfl_xor(p, 8, 64);
        if (kg == 0)
            atomicAdd(&agg[(size_t)d * 64 + obase],
                      p + Q[(size_t)s * 64 + obase]);
    }
}

// combine (scatter-mean + root + bias + relu) and GRU cell
__global__ __launch_bounds__(256) void gru_kernel(float* __restrict__ out,
                                                  const float* __restrict__ agg,
                                                  const float* __restrict__ cnt,
                                                  const float* __restrict__ root,
                                                  const float* __restrict__ cbias,
                                                  const float* __restrict__ wi,
                                                  const float* __restrict__ wh,
                                                  const float* __restrict__ bi,
                                                  const float* __restrict__ bh) {
    __shared__ float root_s[64 * 64];
    __shared__ float h_s[32 * 64];
    __shared__ float m_s[32 * 64];
    int tid = threadIdx.x;
    int lane = tid & 63;
    int wv = __builtin_amdgcn_readfirstlane(tid >> 6);
    int nb = blockIdx.x * 32;
#pragma unroll
    for (int it = 0; it < 4; ++it) {
        int i = it * 1024 + tid * 4;
        *(float4*)&root_s[i] = *(const float4*)&root[i];
    }
#pragma unroll
    for (int it = 0; it < 2; ++it) {
        int i = it * 1024 + tid * 4;
        *(float4*)&h_s[i] = *(const float4*)&out[(size_t)nb * 64 + i];
    }
    __syncthreads();

    int nbase = nb + wv * 8;
    float a[8];
#pragma unroll
    for (int j = 0; j < 8; ++j) {
        int n = nbase + j;
        float c = cnt[n]; c = c > 1.f ? c : 1.f;
        a[j] = agg[(size_t)n * 64 + lane] / c + cbias[lane];
    }
    for (int i = 0; i < 64; ++i) {
        float rv = root_s[i * 64 + lane];
#pragma unroll
        for (int j = 0; j < 8; ++j)
            a[j] = fmaf(h_s[(wv * 8 + j) * 64 + i], rv, a[j]);
    }
#pragma unroll
    for (int j = 0; j < 8; ++j) {
        float m = a[j] > 0.f ? a[j] : 0.f;
        m_s[(wv * 8 + j) * 64 + lane] = m;
    }
    __syncthreads();

    float gir[8], giz[8], gin[8], ghr[8], ghz[8], ghn[8];
    float bi0 = bi[lane], bi1 = bi[64 + lane], bi2 = bi[128 + lane];
    float bh0 = bh[lane], bh1 = bh[64 + lane], bh2 = bh[128 + lane];
#pragma unroll
    for (int j = 0; j < 8; ++j) {
        gir[j] = bi0; giz[j] = bi1; gin[j] = bi2;
        ghr[j] = bh0; ghz[j] = bh1; ghn[j] = bh2;
    }
    for (int i = 0; i < 64; ++i) {
        float w0 = wi[i * 192 + lane];
        float w1 = wi[i * 192 + 64 + lane];
        float w2v = wi[i * 192 + 128 + lane];
        float u0 = wh[i * 192 + lane];
        float u1 = wh[i * 192 + 64 + lane];
        float u2 = wh[i * 192 + 128 + lane];
#pragma unroll
        for (int j = 0; j < 8; ++j) {
            float mi = m_s[(wv * 8 + j) * 64 + i];
            float hi = h_s[(wv * 8 + j) * 64 + i];
            gir[j] = fmaf(mi, w0, gir[j]);
            giz[j] = fmaf(mi, w1, giz[j]);
            gin[j] = fmaf(mi, w2v, gin[j]);
            ghr[j] = fmaf(hi, u0, ghr[j]);
            ghz[j] = fmaf(hi, u1, ghz[j]);
            ghn[j] = fmaf(hi, u2, ghn[j]);
        }
    }
#pragma unroll
    for (int j = 0; j < 8; ++j) {
        int n = nbase + j;
        float rg = 1.f / (1.f + expf(-(gir[j] + ghr[j])));
        float zg = 1.f / (1.f + expf(-(giz[j] + ghz[j])));
        float ng = tanhf(gin[j] + rg * ghn[j]);
        float h = h_s[(wv * 8 + j) * 64 + lane];
        out[(size_t)n * 64 + lane] = (1.f - zg) * ng + zg * h;
    }
}

// Set2Set LSTM cell
__global__ __launch_bounds__(256) void lstm_kernel(const float* __restrict__ q_star,
                                                   float* __restrict__ hl, float* __restrict__ cl,
                                                   const float* __restrict__ wi,
                                                   const float* __restrict__ wh,
                                                   const float* __restrict__ bi,
                                                   const float* __restrict__ bh) {
    int b = blockIdx.x;
    int j = threadIdx.x;
    __shared__ float qs[128], hs[64], g[256];
    if (j < 128) qs[j] = q_star[b * 128 + j];
    if (j < 64) hs[j] = hl[b * 64 + j];
    __syncthreads();
    float acc = bi[j] + bh[j];
#pragma unroll 8
    for (int i = 0; i < 128; ++i) acc = fmaf(qs[i], wi[i * 256 + j], acc);
#pragma unroll 8
    for (int i = 0; i < 64; ++i) acc = fmaf(hs[i], wh[i * 256 + j], acc);
    g[j] = acc;
    __syncthreads();
    if (j < 64) {
        float ig = 1.f / (1.f + expf(-g[j]));
        float fg = 1.f / (1.f + expf(-g[64 + j]));
        float gg = tanhf(g[128 + j]);
        float og = 1.f / (1.f + expf(-g[192 + j]));
        float c = fg * cl[b * 64 + j] + ig * gg;
        cl[b * 64 + j] = c;
        hl[b * 64 + j] = og * tanhf(c);
    }
}

// Set2Set attention
__global__ __launch_bounds__(256) void attn_kernel(const float* __restrict__ out,
                                                   const int* __restrict__ off_b,
                                                   const float* __restrict__ hl,
                                                   float* __restrict__ q_star,
                                                   float* __restrict__ e_ws) {
    int b = blockIdx.x;
    int start = off_b[b], end = off_b[b + 1];
    int t = threadIdx.x;
    __shared__ float q[64];
    __shared__ float red[256];
    __shared__ float racc[256];
    __shared__ float sasum[4];
    if (t < 64) q[t] = hl[b * 64 + t];
    __syncthreads();
    float lmax = -1e30f;
    for (int n = start + t; n < end; n += 256) {
        float acc = 0.f;
#pragma unroll 16
        for (int d2 = 0; d2 < 64; ++d2) acc = fmaf(out[n * 64 + d2], q[d2], acc);
        e_ws[n] = acc;
        lmax = fmaxf(lmax, acc);
    }
    red[t] = lmax;
    __syncthreads();
    for (int s2 = 128; s2 > 0; s2 >>= 1) {
        if (t < s2) red[t] = fmaxf(red[t], red[t + s2]);
        __syncthreads();
    }
    float emax = red[0];
    int w = t >> 6, d = t & 63;
    float rl = 0.f, lasum = 0.f;
    for (int n = start + w; n < end; n += 4) {
        float a = expf(e_ws[n] - emax);
        rl = fmaf(a, out[n * 64 + d], rl);
        if (d == 0) lasum += a;
    }
    racc[t] = rl;
    if (d == 0) sasum[w] = lasum;
    __syncthreads();
    if (t < 64) {
        float r = racc[t] + racc[64 + t] + racc[128 + t] + racc[192 + t];
        float as = sasum[0] + sasum[1] + sasum[2] + sasum[3];
        as = fmaxf(as, 1e-16f);
        q_star[b * 128 + t] = q[t];
        q_star[b * 128 + 64 + t] = r / as;
    }
}

// output head
__global__ __launch_bounds__(64) void head_kernel(const float* __restrict__ q_star,
                                                  const float* __restrict__ w1,
                                                  const float* __restrict__ b1,
                                                  const float* __restrict__ w2,
                                                  const float* __restrict__ b2,
                                                  float* __restrict__ y) {
    int b = blockIdx.x;
    int d = threadIdx.x;
    float qlo = q_star[b * 128 + d];
    float qhi = q_star[b * 128 + 64 + d];
    float acc = b1[d];
#pragma unroll 8
    for (int i = 0; i < 64; ++i) {
        acc = fmaf(__shfl(qlo, i, 64), w1[i * 64 + d], acc);
        acc = fmaf(__shfl(qhi, i, 64), w1[(64 + i) * 64 + d], acc);
    }
    acc = acc > 0.f ? acc : 0.f;
    float p = acc * w2[d];
    for (int off = 32; off > 0; off >>= 1) p += __shfl_down(p, off, 64);
    if (d == 0) y[b] = p + b2[0];
}

extern "C" void kernel_launch(void* const* d_in, const int* in_sizes, int n_in,
                              void* d_out, int out_size, void* d_ws, size_t ws_size,
                              hipStream_t stream) {
    (void)in_sizes; (void)n_in; (void)out_size; (void)ws_size;
    const float* x        = (const float*)d_in[0];
    const float* ea       = (const float*)d_in[1];
    const int*   eidx     = (const int*)d_in[2];
    const int*   batch    = (const int*)d_in[3];
    const float* lin0_w   = (const float*)d_in[4];
    const float* lin0_b   = (const float*)d_in[5];
    const float* mlp_w1   = (const float*)d_in[6];
    const float* mlp_b1   = (const float*)d_in[7];
    const float* mlp_w2   = (const float*)d_in[8];
    const float* mlp_b2   = (const float*)d_in[9];
    const float* conv_root= (const float*)d_in[10];
    const float* conv_bias= (const float*)d_in[11];
    const float* gru_wi   = (const float*)d_in[12];
    const float* gru_wh   = (const float*)d_in[13];
    const float* gru_bi   = (const float*)d_in[14];
    const float* gru_bh   = (const float*)d_in[15];
    const float* lstm_wi  = (const float*)d_in[16];
    const float* lstm_wh  = (const float*)d_in[17];
    const float* lstm_bi  = (const float*)d_in[18];
    const float* lstm_bh  = (const float*)d_in[19];
    const float* lin1_w   = (const float*)d_in[20];
    const float* lin1_b   = (const float*)d_in[21];
    const float* lin2_w   = (const float*)d_in[22];
    const float* lin2_b   = (const float*)d_in[23];
    float* y = (float*)d_out;

    const int* src = eidx;
    const int* dst = eidx + E_;

    char* w = (char*)d_ws;
    auto carve = [&](size_t bytes) {
        char* p = w;
        w += (bytes + 255) & ~(size_t)255;
        return p;
    };
    float* out_buf = (float*)carve((size_t)N_ * DIM_ * 4);
    float* agg     = (float*)carve((size_t)N_ * DIM_ * 4);
    float* Q       = (float*)carve((size_t)N_ * DIM_ * 4);
    float* e_ws    = (float*)carve((size_t)N_ * 4);
    int*   off_b   = (int*)carve((size_t)(B_ + 1) * 4);
    _Float16* h1   = (_Float16*)carve((size_t)E_ * MLP_H_ * 2);
    _Float16* Bf   = (_Float16*)carve((size_t)PC_ * 64 * 2);
    int*   src_off = (int*)carve((size_t)(N_ + 1) * 4);
    int*   eord    = (int*)carve((size_t)E_ * 4);
    // contiguous zero zone (single memset)
    char*  zero0   = w;
    float* cnt     = (float*)carve((size_t)N_ * 4);
    int*   cnt_src = (int*)carve((size_t)N_ * 4);
    int*   cur     = (int*)carve((size_t)N_ * 4);
    float* q_star  = (float*)carve((size_t)B_ * 128 * 4);
    float* hl      = (float*)carve((size_t)B_ * 64 * 4);
    float* cl      = (float*)carve((size_t)B_ * 64 * 4);
    size_t zbytes  = (size_t)(w - zero0);

    hipMemsetAsync(zero0, 0, zbytes, stream);

    lin0_kernel<<<(N_ * DIM_ + 255) / 256, 256, 0, stream>>>(x, lin0_w, lin0_b, out_buf);
    mlp1_kernel<<<(E_ * MLP_H_ + 255) / 256, 256, 0, stream>>>(ea, mlp_w1, mlp_b1, h1);
    cnt_kernel<<<(E_ + 255) / 256, 256, 0, stream>>>(dst, cnt);
    batch_off_kernel<<<1, 256, 0, stream>>>(batch, off_b);
    hist_src<<<(E_ + 255) / 256, 256, 0, stream>>>(src, cnt_src);
    scan_src<<<1, 256, 0, stream>>>(cnt_src, src_off);
    scatter_src<<<(E_ + 255) / 256, 256, 0, stream>>>(src, cur, src_off, eord);
    prep_b<<<(PC_ * 64 + 255) / 256, 256, 0, stream>>>(mlp_w2, Bf);

    dim3 fg(16, (N_ + NB_ - 1) / NB_);
    for (int step = 0; step < 3; ++step) {
        q_kernel<<<(N_ + 3) / 4, 256, 0, stream>>>(out_buf, mlp_b2, Q);
        hipMemsetAsync(agg, 0, (size_t)N_ * DIM_ * 4, stream);
        msg_fused<<<fg, 256, 0, stream>>>(out_buf, Bf, h1, Q, eord, src, dst,
                                          src_off, agg);
        gru_kernel<<<N_ / 32, 256, 0, stream>>>(out_buf, agg, cnt, conv_root, conv_bias,
                                                gru_wi, gru_wh, gru_bi, gru_bh);
    }

    for (int s = 0; s < 3; ++s) {
        lstm_kernel<<<B_, 256, 0, stream>>>(q_star, hl, cl, lstm_wi, lstm_wh, lstm_bi, lstm_bh);
        attn_kernel<<<B_, 256, 0, stream>>>(out_buf, off_b, hl, q_star, e_ws);
    }
    head_kernel<<<B_, 64, 0, stream>>>(q_star, lin1_w, lin1_b, lin2_w, lin2_b, y);
}

// Round 13
// 996.710 us; speedup vs baseline: 3.0252x; 3.0252x over previous
//
#include <hip/hip_runtime.h>
#include <math.h>

// Problem dims (fixed)
#define N_ 20000
#define E_ 100000
#define B_ 128
#define F_IN_ 14
#define DIM_ 64
#define E_FEAT_ 4
#define MLP_H_ 128
#define EWC_ 4096    // DIM*DIM
#define PC_ 8192     // MLP_H * DIM (P columns)

typedef __attribute__((ext_vector_type(4))) float f32x4;
typedef __attribute__((ext_vector_type(8))) _Float16 halfx8;

// ---------------------------------------------------------------------------
// lin0: out[n,d] = relu(x[n,:] @ lin0_w + b)
__global__ void lin0_kernel(const float* __restrict__ x, const float* __restrict__ w,
                            const float* __restrict__ b, float* __restrict__ out) {
    int idx = blockIdx.x * blockDim.x + threadIdx.x;
    if (idx >= N_ * DIM_) return;
    int n = idx >> 6, d = idx & 63;
    float acc = b[d];
#pragma unroll
    for (int f = 0; f < F_IN_; ++f) acc = fmaf(x[n * F_IN_ + f], w[f * DIM_ + d], acc);
    out[idx] = acc > 0.f ? acc : 0.f;
}

// edge MLP layer 1, ROW-major fp16: h1[e*128 + k] = relu(ea[e,:] @ w1 + b1)[k]
__global__ void mlp1_kernel(const float* __restrict__ ea, const float* __restrict__ w1,
                            const float* __restrict__ b1, _Float16* __restrict__ h1) {
    int idx = blockIdx.x * blockDim.x + threadIdx.x;
    if (idx >= E_ * MLP_H_) return;
    int e = idx >> 7, k = idx & 127;
    float acc = b1[k];
#pragma unroll
    for (int f = 0; f < E_FEAT_; ++f) acc = fmaf(ea[e * E_FEAT_ + f], w1[f * MLP_H_ + k], acc);
    h1[idx] = (_Float16)(acc > 0.f ? acc : 0.f);
}

// degree histograms: incoming (float, for mean) + outgoing (int, for sort)
__global__ void deg_kernel(const int* __restrict__ src, const int* __restrict__ dst,
                           float* __restrict__ cnt, int* __restrict__ cnt_src) {
    int e = blockIdx.x * blockDim.x + threadIdx.x;
    if (e >= E_) return;
    atomicAdd(&cnt[dst[e]], 1.0f);
    atomicAdd(&cnt_src[src[e]], 1);
}

// batch is SORTED: off_b[b] = lower_bound(batch, b).
__global__ void batch_off_kernel(const int* __restrict__ batch, int* __restrict__ off_b) {
    int b = threadIdx.x;
    if (b > B_) return;
    int lo = 0, hi = N_;
    while (lo < hi) {
        int mid = (lo + hi) >> 1;
        if (batch[mid] < b) lo = mid + 1; else hi = mid;
    }
    off_b[b] = lo;
}

// exclusive scan over N_ bins -> src_off[0..N_]
__global__ void scan_src(const int* __restrict__ cnt_src, int* __restrict__ src_off) {
    __shared__ int part[256];
    __shared__ int off[257];
    int t = threadIdx.x;
    const int per = (N_ + 255) / 256;
    int base = t * per;
    int s = 0;
    for (int i = 0; i < per; ++i) { int b = base + i; if (b < N_) s += cnt_src[b]; }
    part[t] = s;
    __syncthreads();
    if (t == 0) {
        int a = 0;
        for (int i = 0; i < 256; ++i) { off[i] = a; a += part[i]; }
        off[256] = a;
    }
    __syncthreads();
    int run = off[t];
    for (int i = 0; i < per; ++i) {
        int b = base + i;
        if (b < N_) { src_off[b] = run; run += cnt_src[b]; }
    }
    if (t == 0) src_off[N_] = off[256];
}

// scatter edges into src-sorted order
__global__ void scatter_src(const int* __restrict__ src, int* __restrict__ cur,
                            const int* __restrict__ src_off, int* __restrict__ eord) {
    int e = blockIdx.x * blockDim.x + threadIdx.x;
    if (e >= E_) return;
    int s = src[e];
    int p = src_off[s] + atomicAdd(&cur[s], 1);
    eord[p] = e;
}

// B prep (once), fp16, TRANSPOSED column order c = o*128 + k:
// Bf[c*64 + i] = (fp16) w2[k*4096 + i*64 + o]
__global__ void prep_b(const float* __restrict__ w2, _Float16* __restrict__ Bf) {
    int idx = blockIdx.x * blockDim.x + threadIdx.x;
    if (idx >= PC_ * 64) return;
    int c = idx >> 6, i = idx & 63;
    int o = c >> 7, k = c & 127;
    Bf[idx] = (_Float16)w2[(size_t)k * EWC_ + i * 64 + o];
}

// Q[n,o] = sum_i out[n,i] * b2[i*64+o]; also zero-inits agg (same index space)
__global__ __launch_bounds__(256) void q_kernel(const float* __restrict__ out,
                                                const float* __restrict__ b2,
                                                float* __restrict__ Q,
                                                float* __restrict__ agg) {
    __shared__ float b2s[64 * 64];
    int tid = threadIdx.x;
#pragma unroll
    for (int it = 0; it < 4; ++it) {
        int i = it * 1024 + tid * 4;
        *(float4*)&b2s[i] = *(const float4*)&b2[i];
    }
    __syncthreads();
    int wv = __builtin_amdgcn_readfirstlane(tid >> 6);
    int n = blockIdx.x * 4 + wv;
    if (n >= N_) return;
    int o = tid & 63;
    float ov = out[(size_t)n * 64 + o];
    float acc = 0.f;
#pragma unroll 8
    for (int i = 0; i < 64; ++i) acc = fmaf(__shfl(ov, i, 64), b2s[i * 64 + o], acc);
    Q[(size_t)n * 64 + o] = acc;
    agg[(size_t)n * 64 + o] = 0.f;
}

// ---------------------------------------------------------------------------
// P GEMM via single fp16 MFMA (unchanged from r11): P'[r, c] = out[n0+r,:] @ Bf.
#define STSTR_ 136
__global__ __launch_bounds__(256) void p_gemm_mfma(const float* __restrict__ out,
                                                   const _Float16* __restrict__ Bf,
                                                   _Float16* __restrict__ P,
                                                   int n0, int n1) {
    __shared__ _Float16 st[128 * STSTR_];   // 34.8 KB
    int tid = threadIdx.x;
    int lane = tid & 63;
    int wid = tid >> 6;
    int wm = (wid & 1) * 64;
    int wn = (wid >> 1) * 64;
    int mloc0 = blockIdx.y * 128;
    int nbase = blockIdx.x * 128;
    int lrow = lane & 15, quad = lane >> 4;

    halfx8 bfr[4][2];
#pragma unroll
    for (int nf = 0; nf < 4; ++nf)
#pragma unroll
        for (int ks = 0; ks < 2; ++ks) {
            size_t g = (size_t)(nbase + wn + nf * 16 + lrow) * 64 + ks * 32 + quad * 8;
            bfr[nf][ks] = *(const halfx8*)&Bf[g];
        }

    f32x4 acc[4][4];
#pragma unroll
    for (int a = 0; a < 4; ++a)
#pragma unroll
        for (int b = 0; b < 4; ++b) acc[a][b] = (f32x4){0.f, 0.f, 0.f, 0.f};

#pragma unroll
    for (int mf = 0; mf < 4; ++mf) {
        int gm = n0 + mloc0 + wm + mf * 16 + lrow;
        halfx8 af[2];
#pragma unroll
        for (int ks = 0; ks < 2; ++ks) {
            float v[8];
            if (gm < n1) {
                float4 v0 = *(const float4*)&out[(size_t)gm * 64 + ks * 32 + quad * 8];
                float4 v1 = *(const float4*)&out[(size_t)gm * 64 + ks * 32 + quad * 8 + 4];
                v[0] = v0.x; v[1] = v0.y; v[2] = v0.z; v[3] = v0.w;
                v[4] = v1.x; v[5] = v1.y; v[6] = v1.z; v[7] = v1.w;
            } else {
#pragma unroll
                for (int i = 0; i < 8; ++i) v[i] = 0.f;
            }
#pragma unroll
            for (int i = 0; i < 8; ++i) af[ks][i] = (_Float16)v[i];
        }
#pragma unroll
        for (int nf = 0; nf < 4; ++nf) {
#pragma unroll
            for (int ks = 0; ks < 2; ++ks)
                acc[mf][nf] = __builtin_amdgcn_mfma_f32_16x16x32_f16(
                    af[ks], bfr[nf][ks], acc[mf][nf], 0, 0, 0);
        }
    }

    // stage tile in LDS (C/D frag layout col=lane&15, row=quad*4+reg; m89-verified)
#pragma unroll
    for (int mf = 0; mf < 4; ++mf)
#pragma unroll
        for (int nf = 0; nf < 4; ++nf)
#pragma unroll
            for (int r = 0; r < 4; ++r) {
                int row = wm + mf * 16 + quad * 4 + r;
                int col = wn + nf * 16 + lrow;
                st[row * STSTR_ + col] = (_Float16)acc[mf][nf][r];
            }
    __syncthreads();
#pragma unroll
    for (int it = 0; it < 8; ++it) {
        int chunk = it * 256 + tid;
        int row = chunk >> 4;
        int cb = (chunk & 15) * 8;
        if (n0 + mloc0 + row < n1) {
            int4 v = *(const int4*)&st[row * STSTR_ + cb];
            *(int4*)&P[(size_t)(mloc0 + row) * PC_ + nbase + cb] = v;
        }
    }
}

// ---------------------------------------------------------------------------
// edge_msg via fp16 MFMA (unchanged from r11): per src node, msg-block
// (16 edges x 64 o) = H(16x128) @ P_n'(as B[o][k]). Wave per node.
__global__ __launch_bounds__(256) void edge_msg(const _Float16* __restrict__ P,
                                                const _Float16* __restrict__ h1,
                                                const float* __restrict__ Q,
                                                const int* __restrict__ eord,
                                                const int* __restrict__ dst,
                                                const int* __restrict__ src_off,
                                                float* __restrict__ agg,
                                                int n0, int n1) {
    int wv = __builtin_amdgcn_readfirstlane((int)(threadIdx.x >> 6));
    int r = blockIdx.x * 4 + wv;
    int n = n0 + r;
    if (n >= n1) return;
    int lane = threadIdx.x & 63;
    int lrow = lane & 15, quad = lane >> 4;
    int beg = src_off[n], end2 = src_off[n + 1];
    if (beg == end2) return;
    const _Float16* Pr = P + (size_t)r * PC_;

    halfx8 bf[4][4];
#pragma unroll
    for (int nf = 0; nf < 4; ++nf)
#pragma unroll
        for (int ks = 0; ks < 4; ++ks)
            bf[nf][ks] = *(const halfx8*)&Pr[(nf * 16 + lrow) * 128 + ks * 32 + quad * 8];
    float qv[4];
#pragma unroll
    for (int nf = 0; nf < 4; ++nf) qv[nf] = Q[(size_t)n * 64 + nf * 16 + lrow];

    for (int g = beg; g < end2; g += 16) {
        int gcnt = end2 - g; if (gcnt > 16) gcnt = 16;
        int ei = lrow < gcnt ? lrow : gcnt - 1;
        int ej = eord[g + ei];
        int dv = dst[ej];
        halfx8 af[4];
#pragma unroll
        for (int ks = 0; ks < 4; ++ks)
            af[ks] = *(const halfx8*)&h1[(size_t)ej * 128 + ks * 32 + quad * 8];
        f32x4 acc[4];
#pragma unroll
        for (int nf = 0; nf < 4; ++nf) acc[nf] = (f32x4){0.f, 0.f, 0.f, 0.f};
#pragma unroll
        for (int nf = 0; nf < 4; ++nf)
#pragma unroll
            for (int ks = 0; ks < 4; ++ks)
                acc[nf] = __builtin_amdgcn_mfma_f32_16x16x32_f16(
                    af[ks], bf[nf][ks], acc[nf], 0, 0, 0);
#pragma unroll
        for (int rr = 0; rr < 4; ++rr) {
            int j = quad * 4 + rr;
            int d = __shfl(dv, j, 64);
            if (j < gcnt) {
#pragma unroll
                for (int nf = 0; nf < 4; ++nf)
                    atomicAdd(&agg[(size_t)d * 64 + nf * 16 + lrow],
                              acc[nf][rr] + qv[nf]);
            }
        }
    }
}

// combine (scatter-mean + root + bias + relu) and GRU cell (unchanged)
__global__ __launch_bounds__(256) void gru_kernel(float* __restrict__ out,
                                                  const float* __restrict__ agg,
                                                  const float* __restrict__ cnt,
                                                  const float* __restrict__ root,
                                                  const float* __restrict__ cbias,
                                                  const float* __restrict__ wi,
                                                  const float* __restrict__ wh,
                                                  const float* __restrict__ bi,
                                                  const float* __restrict__ bh) {
    __shared__ float root_s[64 * 64];
    __shared__ float h_s[32 * 64];
    __shared__ float m_s[32 * 64];
    int tid = threadIdx.x;
    int lane = tid & 63;
    int wv = __builtin_amdgcn_readfirstlane(tid >> 6);
    int nb = blockIdx.x * 32;
#pragma unroll
    for (int it = 0; it < 4; ++it) {
        int i = it * 1024 + tid * 4;
        *(float4*)&root_s[i] = *(const float4*)&root[i];
    }
#pragma unroll
    for (int it = 0; it < 2; ++it) {
        int i = it * 1024 + tid * 4;
        *(float4*)&h_s[i] = *(const float4*)&out[(size_t)nb * 64 + i];
    }
    __syncthreads();

    int nbase = nb + wv * 8;
    float a[8];
#pragma unroll
    for (int j = 0; j < 8; ++j) {
        int n = nbase + j;
        float c = cnt[n]; c = c > 1.f ? c : 1.f;
        a[j] = agg[(size_t)n * 64 + lane] / c + cbias[lane];
    }
    for (int i = 0; i < 64; ++i) {
        float rv = root_s[i * 64 + lane];
#pragma unroll
        for (int j = 0; j < 8; ++j)
            a[j] = fmaf(h_s[(wv * 8 + j) * 64 + i], rv, a[j]);
    }
#pragma unroll
    for (int j = 0; j < 8; ++j) {
        float m = a[j] > 0.f ? a[j] : 0.f;
        m_s[(wv * 8 + j) * 64 + lane] = m;
    }
    __syncthreads();

    float gir[8], giz[8], gin[8], ghr[8], ghz[8], ghn[8];
    float bi0 = bi[lane], bi1 = bi[64 + lane], bi2 = bi[128 + lane];
    float bh0 = bh[lane], bh1 = bh[64 + lane], bh2 = bh[128 + lane];
#pragma unroll
    for (int j = 0; j < 8; ++j) {
        gir[j] = bi0; giz[j] = bi1; gin[j] = bi2;
        ghr[j] = bh0; ghz[j] = bh1; ghn[j] = bh2;
    }
    for (int i = 0; i < 64; ++i) {
        float w0 = wi[i * 192 + lane];
        float w1 = wi[i * 192 + 64 + lane];
        float w2v = wi[i * 192 + 128 + lane];
        float u0 = wh[i * 192 + lane];
        float u1 = wh[i * 192 + 64 + lane];
        float u2 = wh[i * 192 + 128 + lane];
#pragma unroll
        for (int j = 0; j < 8; ++j) {
            float mi = m_s[(wv * 8 + j) * 64 + i];
            float hi = h_s[(wv * 8 + j) * 64 + i];
            gir[j] = fmaf(mi, w0, gir[j]);
            giz[j] = fmaf(mi, w1, giz[j]);
            gin[j] = fmaf(mi, w2v, gin[j]);
            ghr[j] = fmaf(hi, u0, ghr[j]);
            ghz[j] = fmaf(hi, u1, ghz[j]);
            ghn[j] = fmaf(hi, u2, ghn[j]);
        }
    }
#pragma unroll
    for (int j = 0; j < 8; ++j) {
        int n = nbase + j;
        float rg = 1.f / (1.f + expf(-(gir[j] + ghr[j])));
        float zg = 1.f / (1.f + expf(-(giz[j] + ghz[j])));
        float ng = tanhf(gin[j] + rg * ghn[j]);
        float h = h_s[(wv * 8 + j) * 64 + lane];
        out[(size_t)n * 64 + lane] = (1.f - zg) * ng + zg * h;
    }
}

// ---------------------------------------------------------------------------
// Fused Set2Set step: LSTM cell -> attention -> q_star update; optional head.
// One block per graph b (256 threads). LSTM output feeds attention via LDS.
__global__ __launch_bounds__(256) void lstm_attn_kernel(
        const float* __restrict__ out, const int* __restrict__ off_b,
        float* __restrict__ hl, float* __restrict__ cl,
        float* __restrict__ q_star, float* __restrict__ e_ws,
        const float* __restrict__ wi, const float* __restrict__ wh,
        const float* __restrict__ bi, const float* __restrict__ bh,
        const float* __restrict__ hw1, const float* __restrict__ hb1,
        const float* __restrict__ hw2, const float* __restrict__ hb2,
        float* __restrict__ y, int do_head) {
    int b = blockIdx.x;
    int t = threadIdx.x;
    __shared__ float qs[128], hs[64], g[256];
    __shared__ float q[64];
    __shared__ float red[256], racc[256], sasum[4];

    // ---- LSTM cell ----
    if (t < 128) qs[t] = q_star[b * 128 + t];
    if (t < 64) hs[t] = hl[b * 64 + t];
    __syncthreads();
    {
        float acc = bi[t] + bh[t];
#pragma unroll 8
        for (int i = 0; i < 128; ++i) acc = fmaf(qs[i], wi[i * 256 + t], acc);
#pragma unroll 8
        for (int i = 0; i < 64; ++i) acc = fmaf(hs[i], wh[i * 256 + t], acc);
        g[t] = acc;
    }
    __syncthreads();
    if (t < 64) {
        float ig = 1.f / (1.f + expf(-g[t]));
        float fg = 1.f / (1.f + expf(-g[64 + t]));
        float gg = tanhf(g[128 + t]);
        float og = 1.f / (1.f + expf(-g[192 + t]));
        float c = fg * cl[b * 64 + t] + ig * gg;
        cl[b * 64 + t] = c;
        float h = og * tanhf(c);
        hl[b * 64 + t] = h;
        q[t] = h;
    }
    __syncthreads();

    // ---- attention ----
    int start = off_b[b], end = off_b[b + 1];
    float lmax = -1e30f;
    for (int n = start + t; n < end; n += 256) {
        float acc = 0.f;
#pragma unroll 16
        for (int d2 = 0; d2 < 64; ++d2) acc = fmaf(out[n * 64 + d2], q[d2], acc);
        e_ws[n] = acc;
        lmax = fmaxf(lmax, acc);
    }
    red[t] = lmax;
    __syncthreads();
    for (int s2 = 128; s2 > 0; s2 >>= 1) {
        if (t < s2) red[t] = fmaxf(red[t], red[t + s2]);
        __syncthreads();
    }
    float emax = red[0];
    int w = t >> 6, d = t & 63;
    float rl = 0.f, lasum = 0.f;
    for (int n = start + w; n < end; n += 4) {
        float a = expf(e_ws[n] - emax);
        rl = fmaf(a, out[n * 64 + d], rl);
        if (d == 0) lasum += a;
    }
    racc[t] = rl;
    if (d == 0) sasum[w] = lasum;
    __syncthreads();
    if (t < 64) {
        float r = racc[t] + racc[64 + t] + racc[128 + t] + racc[192 + t];
        float as = sasum[0] + sasum[1] + sasum[2] + sasum[3];
        as = fmaxf(as, 1e-16f);
        float rv = r / as;
        q_star[b * 128 + t] = q[t];
        q_star[b * 128 + 64 + t] = rv;
        qs[t] = q[t];
        qs[64 + t] = rv;
    }
    __syncthreads();

    // ---- head (final iteration only) ----
    if (do_head && t < 64) {
        float acc = hb1[t];
#pragma unroll 8
        for (int i = 0; i < 128; ++i) acc = fmaf(qs[i], hw1[i * 64 + t], acc);
        acc = acc > 0.f ? acc : 0.f;
        float p = acc * hw2[t];
        for (int off = 32; off > 0; off >>= 1) p += __shfl_down(p, off, 64);
        if (t == 0) y[b] = p + hb2[0];
    }
}

extern "C" void kernel_launch(void* const* d_in, const int* in_sizes, int n_in,
                              void* d_out, int out_size, void* d_ws, size_t ws_size,
                              hipStream_t stream) {
    (void)in_sizes; (void)n_in; (void)out_size;
    const float* x        = (const float*)d_in[0];
    const float* ea       = (const float*)d_in[1];
    const int*   eidx     = (const int*)d_in[2];
    const int*   batch    = (const int*)d_in[3];
    const float* lin0_w   = (const float*)d_in[4];
    const float* lin0_b   = (const float*)d_in[5];
    const float* mlp_w1   = (const float*)d_in[6];
    const float* mlp_b1   = (const float*)d_in[7];
    const float* mlp_w2   = (const float*)d_in[8];
    const float* mlp_b2   = (const float*)d_in[9];
    const float* conv_root= (const float*)d_in[10];
    const float* conv_bias= (const float*)d_in[11];
    const float* gru_wi   = (const float*)d_in[12];
    const float* gru_wh   = (const float*)d_in[13];
    const float* gru_bi   = (const float*)d_in[14];
    const float* gru_bh   = (const float*)d_in[15];
    const float* lstm_wi  = (const float*)d_in[16];
    const float* lstm_wh  = (const float*)d_in[17];
    const float* lstm_bi  = (const float*)d_in[18];
    const float* lstm_bh  = (const float*)d_in[19];
    const float* lin1_w   = (const float*)d_in[20];
    const float* lin1_b   = (const float*)d_in[21];
    const float* lin2_w   = (const float*)d_in[22];
    const float* lin2_b   = (const float*)d_in[23];
    float* y = (float*)d_out;

    const int* src = eidx;
    const int* dst = eidx + E_;

    char* w = (char*)d_ws;
    auto carve = [&](size_t bytes) {
        char* p = w;
        w += (bytes + 255) & ~(size_t)255;
        return p;
    };
    float* out_buf = (float*)carve((size_t)N_ * DIM_ * 4);
    float* agg     = (float*)carve((size_t)N_ * DIM_ * 4);
    float* Q       = (float*)carve((size_t)N_ * DIM_ * 4);
    float* e_ws    = (float*)carve((size_t)N_ * 4);
    int*   off_b   = (int*)carve((size_t)(B_ + 1) * 4);
    _Float16* h1   = (_Float16*)carve((size_t)E_ * MLP_H_ * 2);
    _Float16* Bf   = (_Float16*)carve((size_t)PC_ * 64 * 2);
    int*   src_off = (int*)carve((size_t)(N_ + 1) * 4);
    int*   eord    = (int*)carve((size_t)E_ * 4);
    // contiguous zero zone (single memset)
    char*  zero0   = w;
    float* cnt     = (float*)carve((size_t)N_ * 4);
    int*   cnt_src = (int*)carve((size_t)N_ * 4);
    int*   cur     = (int*)carve((size_t)N_ * 4);
    float* q_star  = (float*)carve((size_t)B_ * 128 * 4);
    float* hl      = (float*)carve((size_t)B_ * 64 * 4);
    float* cl      = (float*)carve((size_t)B_ * 64 * 4);
    size_t zbytes  = (size_t)(w - zero0);

    size_t used = (size_t)(w - (char*)d_ws);
    _Float16* P = (_Float16*)w;
    size_t avail = ws_size > used ? ws_size - used : 0;
    long long nc = (long long)(avail / ((size_t)PC_ * 2));   // fp16 P rows
    if (nc > N_) nc = N_;
    nc &= ~127LL;
    if (nc < 128) nc = 128;
    // balance chunks: equal sizes, multiple of 128
    int nchunks = (N_ + (int)nc - 1) / (int)nc;
    int NC = ((N_ + nchunks - 1) / nchunks + 127) & ~127;

    hipMemsetAsync(zero0, 0, zbytes, stream);

    lin0_kernel<<<(N_ * DIM_ + 255) / 256, 256, 0, stream>>>(x, lin0_w, lin0_b, out_buf);
    mlp1_kernel<<<(E_ * MLP_H_ + 255) / 256, 256, 0, stream>>>(ea, mlp_w1, mlp_b1, h1);
    deg_kernel<<<(E_ + 255) / 256, 256, 0, stream>>>(src, dst, cnt, cnt_src);
    batch_off_kernel<<<1, 256, 0, stream>>>(batch, off_b);
    scan_src<<<1, 256, 0, stream>>>(cnt_src, src_off);
    scatter_src<<<(E_ + 255) / 256, 256, 0, stream>>>(src, cur, src_off, eord);
    prep_b<<<(PC_ * 64 + 255) / 256, 256, 0, stream>>>(mlp_w2, Bf);

    for (int step = 0; step < 3; ++step) {
        q_kernel<<<(N_ + 3) / 4, 256, 0, stream>>>(out_buf, mlp_b2, Q, agg);
        for (int n0 = 0; n0 < N_; n0 += NC) {
            int n1 = n0 + NC < N_ ? n0 + NC : N_;
            dim3 g(PC_ / 128, (n1 - n0 + 127) / 128);
            p_gemm_mfma<<<g, 256, 0, stream>>>(out_buf, Bf, P, n0, n1);
            int nn = n1 - n0;
            edge_msg<<<(nn + 3) / 4, 256, 0, stream>>>(P, h1, Q, eord, dst,
                                                       src_off, agg, n0, n1);
        }
        gru_kernel<<<N_ / 32, 256, 0, stream>>>(out_buf, agg, cnt, conv_root, conv_bias,
                                                gru_wi, gru_wh, gru_bi, gru_bh);
    }

    for (int s = 0; s < 3; ++s) {
        lstm_attn_kernel<<<B_, 256, 0, stream>>>(out_buf, off_b, hl, cl, q_star, e_ws,
                                                 lstm_wi, lstm_wh, lstm_bi, lstm_bh,
                                                 lin1_w, lin1_b, lin2_w, lin2_b,
                                                 y, s == 2 ? 1 : 0);
    }
}